// Round 8
// baseline (269.257 us; speedup 1.0000x reference)
//
#include <hip/hip_runtime.h>
#include <math.h>

#define IN_DIM 128
#define HID    128
#define NN     100000
#define WPACK_BYTES (64 * 64 * 16)       // 64 frags x 64 lanes x 16B = 64 KB
#define WPACK_OFF   64
#define ZBF_OFF     (WPACK_OFF + WPACK_BYTES + 192)          // 256-aligned
#define ZBF_BYTES   (NN * IN_DIM * 2)                        // 25.6 MB

typedef __attribute__((ext_vector_type(8))) __bf16 bf16x8;
typedef __attribute__((ext_vector_type(4))) float  f32x4;

__device__ __forceinline__ unsigned pk2bf(float a, float b) {
    union { __bf16 h[2]; unsigned u; } r;
    r.h[0] = (__bf16)a; r.h[1] = (__bf16)b;   // v_cvt_pk_bf16_f32
    return r.u;
}
__device__ __forceinline__ bf16x8 asbf(uint4 v) { return __builtin_bit_cast(bf16x8, v); }

// dtype probe + W1 -> per-lane bf16 MFMA B-fragment pack
__global__ void prep(const float* __restrict__ W1,
                     const unsigned* __restrict__ ei,
                     uint4* __restrict__ wpack,
                     int* __restrict__ flag, int do_pack) {
    const int t = threadIdx.x;
    if (t < 64) {
        unsigned v = ei[2 * t + 1];
        unsigned long long b = __ballot(v != 0u);
        if (t == 0) flag[0] = (b == 0ull) ? 1 : 0;
    }
    if (!do_pack) return;
    const int lane = t & 63;
    #pragma unroll
    for (int fi = 0; fi < 16; ++fi) {
        const int frag = (t >> 6) + fi * 4;
        const int kc = frag >> 3, jsg = frag & 7;
        const int k0 = kc * 32 + (lane >> 4) * 8;
        const int j  = jsg * 16 + (lane & 15);
        unsigned wv[4];
        #pragma unroll
        for (int p = 0; p < 4; ++p)
            wv[p] = pk2bf(W1[(k0 + 2 * p) * HID + j], W1[(k0 + 2 * p + 1) * HID + j]);
        wpack[frag * 64 + lane] = make_uint4(wv[0], wv[1], wv[2], wv[3]);
    }
}

// z fp32 -> bf16 row-major (256 B per node row)
__global__ void zconv(const float4* __restrict__ z4, uint4* __restrict__ zbf4, int n8) {
    for (int i = blockIdx.x * blockDim.x + threadIdx.x; i < n8; i += gridDim.x * blockDim.x) {
        const float4 a = z4[2 * i], b = z4[2 * i + 1];
        zbf4[i] = make_uint4(pk2bf(a.x, a.y), pk2bf(a.z, a.w),
                             pk2bf(b.x, b.y), pk2bf(b.z, b.w));
    }
}

// -------- fast path: barrier-free, wave-owned 32-edge tiles, direct gather --------
__global__ __launch_bounds__(256, 2)
void lp_wave(const char* __restrict__ zbf,
             const int* __restrict__ ei32,
             const float* __restrict__ b1,
             const float* __restrict__ W2,
             const float* __restrict__ b2,
             float* __restrict__ out,
             const int* __restrict__ flag,
             const uint4* __restrict__ wpack,
             int E, int nwt)
{
    __shared__ uint4 Blds[64 * 64];     // 64 KB: all 64 B-fragments, loaded once
    const int t    = threadIdx.x;
    const int lane = t & 63;
    const int w    = t >> 6;
    const int use64 = flag[0];

    // stage B once per block: 16 uint4 per thread
    #pragma unroll
    for (int i = 0; i < 16; ++i)
        Blds[t + i * 256] = wpack[t + i * 256];
    __syncthreads();                    // the ONLY barrier in this kernel

    const int l4 = lane & 15;           // A-row (edge-sub) / D-col (j-sub)
    const int q  = lane >> 4;           // k-granule / D-row-quad
    // per-lane bias/W2 for this lane's 8 j columns (j = jsg*16 + l4)
    float b1v[8], w2v[8];
    #pragma unroll
    for (int jsg = 0; jsg < 8; ++jsg) { b1v[jsg] = b1[jsg * 16 + l4]; w2v[jsg] = W2[jsg * 16 + l4]; }
    const float b2v = b2[0];

    // wave-tiles of 32 edges; waves fully independent, no inter-wave deps
    for (int wt = blockIdx.x * 4 + w; wt < nwt; wt += gridDim.x * 4) {
        const int eb = wt * 32;
        int e0 = eb + l4;      if (e0 > E - 1) e0 = E - 1;
        int e1 = e0 + 16;      if (e1 > E - 1) e1 = E - 1;
        int s0 = ei32[(long long)e0 << use64];
        int d0 = ei32[(long long)(E + e0) << use64];
        int s1 = ei32[(long long)e1 << use64];
        int d1 = ei32[(long long)(E + e1) << use64];
        s0 = min(max(s0, 0), NN - 1); d0 = min(max(d0, 0), NN - 1);
        s1 = min(max(s1, 0), NN - 1); d1 = min(max(d1, 0), NN - 1);
        // per-lane gather bases: node row (256B) + this lane's 16B granule
        const char* ps0 = zbf + ((long long)s0 << 8) + (q << 4);
        const char* pd0 = zbf + ((long long)d0 << 8) + (q << 4);
        const char* ps1 = zbf + ((long long)s1 << 8) + (q << 4);
        const char* pd1 = zbf + ((long long)d1 << 8) + (q << 4);

        f32x4 acc0[8] = {}, acc1[8] = {};   // mb0/mb1 x 8 jsg
        #pragma unroll
        for (int kc = 0; kc < 8; ++kc) {
            const int off = (kc & 3) << 6;  // 64B per k-chunk within the half-row
            const uint4 a0 = *reinterpret_cast<const uint4*>(((kc < 4) ? ps0 : pd0) + off);
            const uint4 a1 = *reinterpret_cast<const uint4*>(((kc < 4) ? ps1 : pd1) + off);
            #pragma unroll
            for (int jsg = 0; jsg < 8; ++jsg) {
                const uint4 b = Blds[(kc * 8 + jsg) * 64 + lane];   // ds_read_b128
                acc0[jsg] = __builtin_amdgcn_mfma_f32_16x16x32_bf16(
                    asbf(a0), asbf(b), acc0[jsg], 0, 0, 0);
                acc1[jsg] = __builtin_amdgcn_mfma_f32_16x16x32_bf16(
                    asbf(a1), asbf(b), acc1[jsg], 0, 0, 0);
            }
        }

        // layer 2: relu(acc + b1) . W2, summed over 8 jsg in-register,
        // then over the 16 j-lanes via 4 xor-shuffles (within 16-groups)
        float p0[4], p1[4];
        #pragma unroll
        for (int reg = 0; reg < 4; ++reg) {
            float a = 0.f, b = 0.f;
            #pragma unroll
            for (int jsg = 0; jsg < 8; ++jsg) {
                a += fmaxf(acc0[jsg][reg] + b1v[jsg], 0.f) * w2v[jsg];
                b += fmaxf(acc1[jsg][reg] + b1v[jsg], 0.f) * w2v[jsg];
            }
            p0[reg] = a; p1[reg] = b;
        }
        #pragma unroll
        for (int o = 1; o <= 8; o <<= 1)
            #pragma unroll
            for (int reg = 0; reg < 4; ++reg) {
                p0[reg] += __shfl_xor(p0[reg], o);
                p1[reg] += __shfl_xor(p1[reg], o);
            }
        // lane (q, l4<4) stores edges eb + mb*16 + q*4 + l4
        if (l4 < 4) {
            const float r0 = (l4 == 0) ? p0[0] : (l4 == 1) ? p0[1] : (l4 == 2) ? p0[2] : p0[3];
            const float r1 = (l4 == 0) ? p1[0] : (l4 == 1) ? p1[1] : (l4 == 2) ? p1[2] : p1[3];
            const int ea = eb + q * 4 + l4;
            const int eb2 = ea + 16;
            if (ea  < E) out[ea]  = 1.f / (1.f + expf(-(r0 + b2v)));
            if (eb2 < E) out[eb2] = 1.f / (1.f + expf(-(r1 + b2v)));
        }
    }
}

// ---------------- fallback path (R5 kernel, fp32 z gather) ----------------
__global__ __launch_bounds__(256, 3)
void lp_main(const float* __restrict__ z,
             const int* __restrict__ ei32,
             const float* __restrict__ W1,
             const float* __restrict__ b1,
             const float* __restrict__ W2,
             const float* __restrict__ b2,
             float* __restrict__ out,
             const int* __restrict__ flag,
             const uint4* __restrict__ wpack,
             int use_ws, int E, int ntiles)
{
    __shared__ uint4 ldsA_[64 * 512 / 16];
    __shared__ float part[4][64];
    char* ldsc = (char*)ldsA_;

    const int t    = threadIdx.x;
    const int lane = t & 63;
    const int w    = t >> 6;
    const int use64 = flag[0];

    uint4 Bf[8][2];
    if (use_ws) {
        #pragma unroll
        for (int kc = 0; kc < 8; ++kc)
            #pragma unroll
            for (int js = 0; js < 2; ++js)
                Bf[kc][js] = wpack[(kc * 8 + (w * 2 + js)) * 64 + lane];
    } else {
        #pragma unroll
        for (int kc = 0; kc < 8; ++kc)
            #pragma unroll
            for (int js = 0; js < 2; ++js) {
                const int k0 = kc * 32 + (lane >> 4) * 8;
                const int j  = (w * 2 + js) * 16 + (lane & 15);
                unsigned wv[4];
                #pragma unroll
                for (int p = 0; p < 4; ++p)
                    wv[p] = pk2bf(W1[(k0 + 2 * p) * HID + j],
                                  W1[(k0 + 2 * p + 1) * HID + j]);
                Bf[kc][js] = make_uint4(wv[0], wv[1], wv[2], wv[3]);
            }
    }

    const int e_r = lane & 15;
    const int q   = lane >> 4;
    const int m16 = q * 16;
    const float b1v0 = b1[w * 32 + e_r], b1v1 = b1[w * 32 + 16 + e_r];
    const float w2v0 = W2[w * 32 + e_r], w2v1 = W2[w * 32 + 16 + e_r];
    const float b2v  = b2[0];

    for (int tile = blockIdx.x; tile < ntiles; tile += gridDim.x) {
        const int e0 = tile * 64;
        #pragma unroll 8
        for (int i = 0; i < 16; ++i) {
            const int el = i * 4 + w;
            int e = e0 + el; if (e > E - 1) e = E - 1;
            const int word = (lane < 32) ? e : (E + e);
            int node = ei32[(long long)word << use64];
            node = min(max(node, 0), NN - 1);
            const float4 v = *reinterpret_cast<const float4*>(
                &z[node * IN_DIM + (lane & 31) * 4]);
            const int byte = el * 512 + ((lane * 8) ^ ((el & 7) << 4));
            *reinterpret_cast<uint2*>(ldsc + byte) =
                make_uint2(pk2bf(v.x, v.y), pk2bf(v.z, v.w));
        }
        __syncthreads();

        f32x4 acc[4][2] = {};
        #pragma unroll
        for (int kc = 0; kc < 8; ++kc) {
            #pragma unroll
            for (int es = 0; es < 4; ++es) {
                const int row  = es * 16 + e_r;
                const int byte = row * 512 + ((kc * 64 + m16) ^ ((row & 7) << 4));
                const bf16x8 a = *reinterpret_cast<const bf16x8*>(ldsc + byte);
                acc[es][0] = __builtin_amdgcn_mfma_f32_16x16x32_bf16(
                    a, asbf(Bf[kc][0]), acc[es][0], 0, 0, 0);
                acc[es][1] = __builtin_amdgcn_mfma_f32_16x16x32_bf16(
                    a, asbf(Bf[kc][1]), acc[es][1], 0, 0, 0);
            }
        }

        float v16[16];
        #pragma unroll
        for (int es = 0; es < 4; ++es)
            #pragma unroll
            for (int reg = 0; reg < 4; ++reg)
                v16[es * 4 + reg] = fmaxf(acc[es][0][reg] + b1v0, 0.f) * w2v0
                                  + fmaxf(acc[es][1][reg] + b1v1, 0.f) * w2v1;
        #pragma unroll
        for (int rnd = 0; rnd < 4; ++rnd) {
            const int o = 1 << rnd;
            const int hl = 8 >> rnd;
            #pragma unroll
            for (int i = 0; i < hl; ++i) {
                const float a = v16[i], b = v16[i + hl];
                const float s = (lane & o) ? a : b;
                const float r = __shfl_xor(s, o);
                v16[i] = ((lane & o) ? b : a) + r;
            }
        }
        {
            const int lx  = lane & 15;
            const int idx = ((lx & 1) << 3) | ((lx & 2) << 1) | ((lx & 4) >> 1) | ((lx & 8) >> 3);
            const int edge = (idx >> 2) * 16 + q * 4 + (idx & 3);
            part[w][edge] = v16[0];
        }
        __syncthreads();

        if (t < 64) {
            const int e = e0 + t;
            if (e < E) {
                const float s = part[0][t] + part[1][t] + part[2][t] + part[3][t] + b2v;
                out[e] = 1.f / (1.f + expf(-s));
            }
        }
    }
}

extern "C" void kernel_launch(void* const* d_in, const int* in_sizes, int n_in,
                              void* d_out, int out_size, void* d_ws, size_t ws_size,
                              hipStream_t stream) {
    const float* z  = (const float*)d_in[0];
    const void*  ei = d_in[1];
    const float* W1 = (const float*)d_in[2];
    const float* b1 = (const float*)d_in[3];
    const float* W2 = (const float*)d_in[4];
    const float* b2 = (const float*)d_in[5];
    float* out = (float*)d_out;
    int*   flag  = (int*)d_ws;
    uint4* wpack = (uint4*)((char*)d_ws + WPACK_OFF);
    char*  zbf   = (char*)d_ws + ZBF_OFF;

    const int E = in_sizes[1] / 2;
    const int use_ws  = (ws_size >= (size_t)(WPACK_OFF + WPACK_BYTES)) ? 1 : 0;
    const int use_zbf = (ws_size >= (size_t)(ZBF_OFF + ZBF_BYTES)) ? 1 : 0;

    hipLaunchKernelGGL(prep, dim3(1), dim3(256), 0, stream,
                       W1, (const unsigned*)ei, wpack, flag, use_ws);

    if (use_zbf) {
        const int n8 = NN * IN_DIM / 8;
        hipLaunchKernelGGL(zconv, dim3(4096), dim3(256), 0, stream,
                           (const float4*)z, (uint4*)zbf, n8);
        const int nwt = (E + 31) / 32;
        int grid = (nwt + 3) / 4; if (grid > 512) grid = 512;   // 2 blocks/CU (64KB LDS)
        hipLaunchKernelGGL(lp_wave, dim3(grid), dim3(256), 0, stream,
                           zbf, (const int*)ei, b1, W2, b2, out, flag, wpack, E, nwt);
    } else {
        const int ntiles = (E + 63) / 64;
        const int grid = (ntiles < 768) ? ntiles : 768;
        hipLaunchKernelGGL(lp_main, dim3(grid), dim3(256), 0, stream,
                           z, (const int*)ei, W1, b1, W2, b2, out, flag, wpack,
                           use_ws, E, ntiles);
    }
}

// Round 9
// 161.156 us; speedup vs baseline: 1.6708x; 1.6708x over previous
//
#include <hip/hip_runtime.h>
#include <math.h>

#define IN_DIM 128
#define HID    128
#define NN     100000
#define WPACK_BYTES (64 * 64 * 16)       // 64 frags x 64 lanes x 16B = 64 KB
#define WPACK_OFF   64
#define UBF_OFF     (WPACK_OFF + WPACK_BYTES + 192)   // 256-aligned
#define UBF_BYTES   (NN * HID * 2)                    // 25.6 MB
#define VBF_OFF     (UBF_OFF + UBF_BYTES)
#define VBF_BYTES   (NN * HID * 2)                    // 25.6 MB

typedef __attribute__((ext_vector_type(8))) __bf16 bf16x8;
typedef __attribute__((ext_vector_type(4))) float  f32x4;

__device__ __forceinline__ unsigned pk2bf(float a, float b) {
    union { __bf16 h[2]; unsigned u; } r;
    r.h[0] = (__bf16)a; r.h[1] = (__bf16)b;   // v_cvt_pk_bf16_f32
    return r.u;
}
__device__ __forceinline__ bf16x8 asbf(uint4 v) { return __builtin_bit_cast(bf16x8, v); }
__device__ __forceinline__ float bflo(unsigned w) { return __uint_as_float(w << 16); }
__device__ __forceinline__ float bfhi(unsigned w) { return __uint_as_float(w & 0xffff0000u); }

// dtype probe + W1 -> per-lane bf16 MFMA B-fragment pack
__global__ void prep(const float* __restrict__ W1,
                     const unsigned* __restrict__ ei,
                     uint4* __restrict__ wpack,
                     int* __restrict__ flag, int do_pack) {
    const int t = threadIdx.x;
    if (t < 64) {
        unsigned v = ei[2 * t + 1];
        unsigned long long b = __ballot(v != 0u);
        if (t == 0) flag[0] = (b == 0ull) ? 1 : 0;
    }
    if (!do_pack) return;
    const int lane = t & 63;
    #pragma unroll
    for (int fi = 0; fi < 16; ++fi) {
        const int frag = (t >> 6) + fi * 4;
        const int kc = frag >> 3, jsg = frag & 7;
        const int k0 = kc * 32 + (lane >> 4) * 8;
        const int j  = jsg * 16 + (lane & 15);
        unsigned wv[4];
        #pragma unroll
        for (int p = 0; p < 4; ++p)
            wv[p] = pk2bf(W1[(k0 + 2 * p) * HID + j], W1[(k0 + 2 * p + 1) * HID + j]);
        wpack[frag * 64 + lane] = make_uint4(wv[0], wv[1], wv[2], wv[3]);
    }
}

// U = z * W1[0:128,:], V = z * W1[128:256,:]  (per-node, bf16 outputs)
// Tile: 64 node rows per block; wave w owns rows w*16..w*16+15.
__global__ __launch_bounds__(256, 2)
void uv_gemm(const float* __restrict__ z,
             const uint4* __restrict__ wpack,
             char* __restrict__ ubf, char* __restrict__ vbf,
             int ntiles)
{
    __shared__ char A[64 * 256];     // 16 KB, XOR-swizzled rows (byte ^= (row&7)<<4)
    const int t = threadIdx.x, lane = t & 63, w = t >> 6;
    const int l4 = lane & 15, q = lane >> 4;

    for (int tile = blockIdx.x; tile < ntiles; tile += gridDim.x) {
        const int node0 = tile * 64;

        // stage: thread t -> row t>>2, granules (t&3)+4i; fp32 load + cvt
        const int srow = t >> 2;
        const int snode = min(node0 + srow, NN - 1);
        #pragma unroll
        for (int i = 0; i < 4; ++i) {
            const int gr = (t & 3) + 4 * i;              // 16B bf16 granule = 8 dims
            const float4 a = *reinterpret_cast<const float4*>(&z[snode * IN_DIM + gr * 8]);
            const float4 b = *reinterpret_cast<const float4*>(&z[snode * IN_DIM + gr * 8 + 4]);
            *reinterpret_cast<uint4*>(A + srow * 256 + ((gr * 16) ^ ((srow & 7) << 4))) =
                make_uint4(pk2bf(a.x, a.y), pk2bf(a.z, a.w), pk2bf(b.x, b.y), pk2bf(b.z, b.w));
        }
        __syncthreads();

        f32x4 au[8] = {}, av[8] = {};
        #pragma unroll
        for (int kc = 0; kc < 4; ++kc) {
            const int r = w * 16 + l4;
            const bf16x8 a = *reinterpret_cast<const bf16x8*>(
                A + r * 256 + ((kc * 64 + q * 16) ^ ((r & 7) << 4)));
            #pragma unroll
            for (int jsg = 0; jsg < 8; ++jsg) {
                au[jsg] = __builtin_amdgcn_mfma_f32_16x16x32_bf16(
                    a, asbf(wpack[(kc * 8 + jsg) * 64 + lane]), au[jsg], 0, 0, 0);
                av[jsg] = __builtin_amdgcn_mfma_f32_16x16x32_bf16(
                    a, asbf(wpack[((kc + 4) * 8 + jsg) * 64 + lane]), av[jsg], 0, 0, 0);
            }
        }

        // write: D row = w*16 + q*4 + reg, col = jsg*16 + l4; pair cols via shfl
        #pragma unroll
        for (int jsg = 0; jsg < 8; ++jsg)
            #pragma unroll
            for (int reg = 0; reg < 4; ++reg) {
                const float uu = au[jsg][reg], vv = av[jsg][reg];
                const float pu = __shfl_xor(uu, 1), pv = __shfl_xor(vv, 1);
                const int r = w * 16 + q * 4 + reg;
                const int node = node0 + r;
                if (!(l4 & 1) && node < NN) {
                    const long long nb = (long long)node * 256 + (jsg * 16 + l4) * 2;
                    *reinterpret_cast<unsigned*>(ubf + nb) = pk2bf(uu, pu);
                    *reinterpret_cast<unsigned*>(vbf + nb) = pk2bf(vv, pv);
                }
            }
        __syncthreads();
    }
}

// Edge phase: pure streaming gather. 16 lanes cover one edge's 128 dims
// (granule g = lane&15, 8 dims each); reduce via 4 xor-shuffles.
__global__ __launch_bounds__(256)
void lp_edge(const char* __restrict__ ubf, const char* __restrict__ vbf,
             const int* __restrict__ ei32,
             const float* __restrict__ b1, const float* __restrict__ W2,
             const float* __restrict__ b2, float* __restrict__ out,
             const int* __restrict__ flag, int E)
{
    const int t = threadIdx.x;
    const int g = t & 15;
    const int use64 = flag[0];
    const float4 b1a = *reinterpret_cast<const float4*>(&b1[g * 8]);
    const float4 b1b = *reinterpret_cast<const float4*>(&b1[g * 8 + 4]);
    const float4 w2a = *reinterpret_cast<const float4*>(&W2[g * 8]);
    const float4 w2b = *reinterpret_cast<const float4*>(&W2[g * 8 + 4]);
    const float b2v = b2[0];

    for (int e = blockIdx.x * 16 + (t >> 4); e < E; e += gridDim.x * 16) {
        int s = ei32[(long long)e << use64];
        int d = ei32[(long long)(E + e) << use64];
        s = min(max(s, 0), NN - 1);
        d = min(max(d, 0), NN - 1);
        const uint4 uu = *reinterpret_cast<const uint4*>(ubf + (long long)s * 256 + g * 16);
        const uint4 vv = *reinterpret_cast<const uint4*>(vbf + (long long)d * 256 + g * 16);

        float acc;
        acc  = fmaxf(bflo(uu.x) + bflo(vv.x) + b1a.x, 0.f) * w2a.x;
        acc += fmaxf(bfhi(uu.x) + bfhi(vv.x) + b1a.y, 0.f) * w2a.y;
        acc += fmaxf(bflo(uu.y) + bflo(vv.y) + b1a.z, 0.f) * w2a.z;
        acc += fmaxf(bfhi(uu.y) + bfhi(vv.y) + b1a.w, 0.f) * w2a.w;
        acc += fmaxf(bflo(uu.z) + bflo(vv.z) + b1b.x, 0.f) * w2b.x;
        acc += fmaxf(bfhi(uu.z) + bfhi(vv.z) + b1b.y, 0.f) * w2b.y;
        acc += fmaxf(bflo(uu.w) + bflo(vv.w) + b1b.z, 0.f) * w2b.z;
        acc += fmaxf(bfhi(uu.w) + bfhi(vv.w) + b1b.w, 0.f) * w2b.w;

        acc += __shfl_xor(acc, 1);
        acc += __shfl_xor(acc, 2);
        acc += __shfl_xor(acc, 4);
        acc += __shfl_xor(acc, 8);
        if (g == 0) out[e] = 1.f / (1.f + expf(-(acc + b2v)));
    }
}

// ---------------- fallback (R5-proven fp32-gather kernel) ----------------
__global__ __launch_bounds__(256, 3)
void lp_main(const float* __restrict__ z,
             const int* __restrict__ ei32,
             const float* __restrict__ W1,
             const float* __restrict__ b1,
             const float* __restrict__ W2,
             const float* __restrict__ b2,
             float* __restrict__ out,
             const int* __restrict__ flag,
             const uint4* __restrict__ wpack,
             int use_ws, int E, int ntiles)
{
    __shared__ uint4 ldsA_[64 * 512 / 16];
    __shared__ float part[4][64];
    char* ldsc = (char*)ldsA_;

    const int t = threadIdx.x, lane = t & 63, w = t >> 6;
    const int use64 = flag[0];

    uint4 Bf[8][2];
    if (use_ws) {
        #pragma unroll
        for (int kc = 0; kc < 8; ++kc)
            #pragma unroll
            for (int js = 0; js < 2; ++js)
                Bf[kc][js] = wpack[(kc * 8 + (w * 2 + js)) * 64 + lane];
    } else {
        #pragma unroll
        for (int kc = 0; kc < 8; ++kc)
            #pragma unroll
            for (int js = 0; js < 2; ++js) {
                const int k0 = kc * 32 + (lane >> 4) * 8;
                const int j  = (w * 2 + js) * 16 + (lane & 15);
                unsigned wv[4];
                #pragma unroll
                for (int p = 0; p < 4; ++p)
                    wv[p] = pk2bf(W1[(k0 + 2 * p) * HID + j],
                                  W1[(k0 + 2 * p + 1) * HID + j]);
                Bf[kc][js] = make_uint4(wv[0], wv[1], wv[2], wv[3]);
            }
    }

    const int e_r = lane & 15, q = lane >> 4, m16 = q * 16;
    const float b1v0 = b1[w * 32 + e_r], b1v1 = b1[w * 32 + 16 + e_r];
    const float w2v0 = W2[w * 32 + e_r], w2v1 = W2[w * 32 + 16 + e_r];
    const float b2v  = b2[0];

    for (int tile = blockIdx.x; tile < ntiles; tile += gridDim.x) {
        const int e0 = tile * 64;
        #pragma unroll 8
        for (int i = 0; i < 16; ++i) {
            const int el = i * 4 + w;
            int e = e0 + el; if (e > E - 1) e = E - 1;
            const int word = (lane < 32) ? e : (E + e);
            int node = ei32[(long long)word << use64];
            node = min(max(node, 0), NN - 1);
            const float4 v = *reinterpret_cast<const float4*>(
                &z[node * IN_DIM + (lane & 31) * 4]);
            const int byte = el * 512 + ((lane * 8) ^ ((el & 7) << 4));
            *reinterpret_cast<uint2*>(ldsc + byte) =
                make_uint2(pk2bf(v.x, v.y), pk2bf(v.z, v.w));
        }
        __syncthreads();

        f32x4 acc[4][2] = {};
        #pragma unroll
        for (int kc = 0; kc < 8; ++kc) {
            #pragma unroll
            for (int es = 0; es < 4; ++es) {
                const int row  = es * 16 + e_r;
                const int byte = row * 512 + ((kc * 64 + m16) ^ ((row & 7) << 4));
                const bf16x8 a = *reinterpret_cast<const bf16x8*>(ldsc + byte);
                acc[es][0] = __builtin_amdgcn_mfma_f32_16x16x32_bf16(
                    a, asbf(Bf[kc][0]), acc[es][0], 0, 0, 0);
                acc[es][1] = __builtin_amdgcn_mfma_f32_16x16x32_bf16(
                    a, asbf(Bf[kc][1]), acc[es][1], 0, 0, 0);
            }
        }

        float v16[16];
        #pragma unroll
        for (int es = 0; es < 4; ++es)
            #pragma unroll
            for (int reg = 0; reg < 4; ++reg)
                v16[es * 4 + reg] = fmaxf(acc[es][0][reg] + b1v0, 0.f) * w2v0
                                  + fmaxf(acc[es][1][reg] + b1v1, 0.f) * w2v1;
        #pragma unroll
        for (int rnd = 0; rnd < 4; ++rnd) {
            const int o = 1 << rnd, hl = 8 >> rnd;
            #pragma unroll
            for (int i = 0; i < hl; ++i) {
                const float a = v16[i], b = v16[i + hl];
                const float s = (lane & o) ? a : b;
                const float r = __shfl_xor(s, o);
                v16[i] = ((lane & o) ? b : a) + r;
            }
        }
        {
            const int lx  = lane & 15;
            const int idx = ((lx & 1) << 3) | ((lx & 2) << 1) | ((lx & 4) >> 1) | ((lx & 8) >> 3);
            const int edge = (idx >> 2) * 16 + q * 4 + (idx & 3);
            part[w][edge] = v16[0];
        }
        __syncthreads();

        if (t < 64) {
            const int e = e0 + t;
            if (e < E) {
                const float s = part[0][t] + part[1][t] + part[2][t] + part[3][t] + b2v;
                out[e] = 1.f / (1.f + expf(-s));
            }
        }
    }
}

extern "C" void kernel_launch(void* const* d_in, const int* in_sizes, int n_in,
                              void* d_out, int out_size, void* d_ws, size_t ws_size,
                              hipStream_t stream) {
    const float* z  = (const float*)d_in[0];
    const void*  ei = d_in[1];
    const float* W1 = (const float*)d_in[2];
    const float* b1 = (const float*)d_in[3];
    const float* W2 = (const float*)d_in[4];
    const float* b2 = (const float*)d_in[5];
    float* out = (float*)d_out;
    int*   flag  = (int*)d_ws;
    uint4* wpack = (uint4*)((char*)d_ws + WPACK_OFF);
    char*  ubf   = (char*)d_ws + UBF_OFF;
    char*  vbf   = (char*)d_ws + VBF_OFF;

    const int E = in_sizes[1] / 2;
    const int use_ws = (ws_size >= (size_t)(WPACK_OFF + WPACK_BYTES)) ? 1 : 0;
    const int use_uv = (ws_size >= (size_t)(VBF_OFF + VBF_BYTES)) ? 1 : 0;

    hipLaunchKernelGGL(prep, dim3(1), dim3(256), 0, stream,
                       W1, (const unsigned*)ei, wpack, flag, use_ws);

    if (use_uv) {
        const int ntiles = (NN + 63) / 64;                 // 1563
        const int g1 = (ntiles < 1024) ? ntiles : 1024;
        hipLaunchKernelGGL(uv_gemm, dim3(g1), dim3(256), 0, stream,
                           z, wpack, ubf, vbf, ntiles);
        hipLaunchKernelGGL(lp_edge, dim3(2048), dim3(256), 0, stream,
                           ubf, vbf, (const int*)ei, b1, W2, b2, out, flag, E);
    } else {
        const int ntiles = (E + 63) / 64;
        const int grid = (ntiles < 768) ? ntiles : 768;
        hipLaunchKernelGGL(lp_main, dim3(grid), dim3(256), 0, stream,
                           z, (const int*)ei, W1, b1, W2, b2, out, flag, wpack,
                           use_ws, E, ntiles);
    }
}

// Round 10
// 150.809 us; speedup vs baseline: 1.7854x; 1.0686x over previous
//
#include <hip/hip_runtime.h>
#include <math.h>

#define IN_DIM 128
#define HID    128
#define NN     100000
#define WPACK_BYTES (64 * 64 * 16)       // 64 frags x 64 lanes x 16B = 64 KB
#define WPACK_OFF   64
#define UBF_OFF     (WPACK_OFF + WPACK_BYTES + 192)   // 256-aligned
#define UBF_BYTES   (NN * HID * 2)                    // 25.6 MB
#define VBF_OFF     (UBF_OFF + UBF_BYTES)
#define VBF_BYTES   (NN * HID * 2)                    // 25.6 MB

typedef __attribute__((ext_vector_type(8))) __bf16 bf16x8;
typedef __attribute__((ext_vector_type(4))) float  f32x4;

__device__ __forceinline__ unsigned pk2bf(float a, float b) {
    union { __bf16 h[2]; unsigned u; } r;
    r.h[0] = (__bf16)a; r.h[1] = (__bf16)b;   // v_cvt_pk_bf16_f32
    return r.u;
}
__device__ __forceinline__ bf16x8 asbf(uint4 v) { return __builtin_bit_cast(bf16x8, v); }
__device__ __forceinline__ float bflo(unsigned w) { return __uint_as_float(w << 16); }
__device__ __forceinline__ float bfhi(unsigned w) { return __uint_as_float(w & 0xffff0000u); }

// dtype probe + W1 -> per-lane bf16 MFMA B-fragment pack
__global__ void prep(const float* __restrict__ W1,
                     const unsigned* __restrict__ ei,
                     uint4* __restrict__ wpack,
                     int* __restrict__ flag, int do_pack) {
    const int t = threadIdx.x;
    if (t < 64) {
        unsigned v = ei[2 * t + 1];
        unsigned long long b = __ballot(v != 0u);
        if (t == 0) flag[0] = (b == 0ull) ? 1 : 0;
    }
    if (!do_pack) return;
    const int lane = t & 63;
    #pragma unroll
    for (int fi = 0; fi < 16; ++fi) {
        const int frag = (t >> 6) + fi * 4;
        const int kc = frag >> 3, jsg = frag & 7;
        const int k0 = kc * 32 + (lane >> 4) * 8;
        const int j  = jsg * 16 + (lane & 15);
        unsigned wv[4];
        #pragma unroll
        for (int p = 0; p < 4; ++p)
            wv[p] = pk2bf(W1[(k0 + 2 * p) * HID + j], W1[(k0 + 2 * p + 1) * HID + j]);
        wpack[frag * 64 + lane] = make_uint4(wv[0], wv[1], wv[2], wv[3]);
    }
}

// U = z*W1[0:128,:], V = z*W1[128:256,:] per node, bf16, PERMUTED row layout:
// row byte l4*16 + jsg*2 holds col j = jsg*16 + l4. One barrier total.
__global__ __launch_bounds__(256, 2)
void uv_gemm(const float* __restrict__ z,
             const uint4* __restrict__ wpack,
             char* __restrict__ ubf, char* __restrict__ vbf,
             int ntiles)
{
    __shared__ uint4 Wlds[64 * 64];     // all 64 B-frags, 64 KB, staged once
    const int t = threadIdx.x, lane = t & 63, w = t >> 6;
    const int l4 = lane & 15, q = lane >> 4;

    #pragma unroll
    for (int i = 0; i < 16; ++i)
        Wlds[t + i * 256] = wpack[t + i * 256];
    __syncthreads();                    // only barrier in this kernel

    for (int tile = blockIdx.x; tile < ntiles; tile += gridDim.x) {
        const int node0 = tile * 64;
        const int arow  = min(node0 + w * 16 + l4, NN - 1);   // this lane's A-row
        const float* zr = z + (long long)arow * IN_DIM + q * 8;

        f32x4 au[8] = {}, av[8] = {};
        #pragma unroll
        for (int kc = 0; kc < 4; ++kc) {
            // A-frag: dims kc*32 + q*8 .. +7, fp32 -> bf16 in-register
            const float4 f0 = *reinterpret_cast<const float4*>(zr + kc * 32);
            const float4 f1 = *reinterpret_cast<const float4*>(zr + kc * 32 + 4);
            const bf16x8 a = asbf(make_uint4(pk2bf(f0.x, f0.y), pk2bf(f0.z, f0.w),
                                             pk2bf(f1.x, f1.y), pk2bf(f1.z, f1.w)));
            #pragma unroll
            for (int jsg = 0; jsg < 8; ++jsg) {
                au[jsg] = __builtin_amdgcn_mfma_f32_16x16x32_bf16(
                    a, asbf(Wlds[(kc * 8 + jsg) * 64 + lane]), au[jsg], 0, 0, 0);
                av[jsg] = __builtin_amdgcn_mfma_f32_16x16x32_bf16(
                    a, asbf(Wlds[((kc + 4) * 8 + jsg) * 64 + lane]), av[jsg], 0, 0, 0);
            }
        }

        // store: D row = node0 + w*16 + q*4 + reg; lane packs its 8 jsg values
        // into one uint4 -> 16 lanes cover the full 256B row, fully coalesced.
        #pragma unroll
        for (int reg = 0; reg < 4; ++reg) {
            const int n = node0 + w * 16 + q * 4 + reg;
            if (n < NN) {
                const long long nb = (long long)n * 256 + l4 * 16;
                *reinterpret_cast<uint4*>(ubf + nb) =
                    make_uint4(pk2bf(au[0][reg], au[1][reg]), pk2bf(au[2][reg], au[3][reg]),
                               pk2bf(au[4][reg], au[5][reg]), pk2bf(au[6][reg], au[7][reg]));
                *reinterpret_cast<uint4*>(vbf + nb) =
                    make_uint4(pk2bf(av[0][reg], av[1][reg]), pk2bf(av[2][reg], av[3][reg]),
                               pk2bf(av[4][reg], av[5][reg]), pk2bf(av[6][reg], av[7][reg]));
            }
        }
    }
}

// Edge phase: pure streaming gather over permuted U/V rows.
// 16 lanes per edge; lane g reads 16B = cols {jsg*16+g : jsg=0..7}.
__global__ __launch_bounds__(256)
void lp_edge(const char* __restrict__ ubf, const char* __restrict__ vbf,
             const int* __restrict__ ei32,
             const float* __restrict__ b1, const float* __restrict__ W2,
             const float* __restrict__ b2, float* __restrict__ out,
             const int* __restrict__ flag, int E)
{
    const int t = threadIdx.x;
    const int g = t & 15;
    const int use64 = flag[0];
    float b1p[8], w2p[8];
    #pragma unroll
    for (int jsg = 0; jsg < 8; ++jsg) {
        b1p[jsg] = b1[jsg * 16 + g];
        w2p[jsg] = W2[jsg * 16 + g];
    }
    const float b2v = b2[0];

    for (int e = blockIdx.x * 16 + (t >> 4); e < E; e += gridDim.x * 16) {
        int s = ei32[(long long)e << use64];
        int d = ei32[(long long)(E + e) << use64];
        s = min(max(s, 0), NN - 1);
        d = min(max(d, 0), NN - 1);
        const uint4 uu = *reinterpret_cast<const uint4*>(ubf + (long long)s * 256 + g * 16);
        const uint4 vv = *reinterpret_cast<const uint4*>(vbf + (long long)d * 256 + g * 16);

        float acc;
        acc  = fmaxf(bflo(uu.x) + bflo(vv.x) + b1p[0], 0.f) * w2p[0];
        acc += fmaxf(bfhi(uu.x) + bfhi(vv.x) + b1p[1], 0.f) * w2p[1];
        acc += fmaxf(bflo(uu.y) + bflo(vv.y) + b1p[2], 0.f) * w2p[2];
        acc += fmaxf(bfhi(uu.y) + bfhi(vv.y) + b1p[3], 0.f) * w2p[3];
        acc += fmaxf(bflo(uu.z) + bflo(vv.z) + b1p[4], 0.f) * w2p[4];
        acc += fmaxf(bfhi(uu.z) + bfhi(vv.z) + b1p[5], 0.f) * w2p[5];
        acc += fmaxf(bflo(uu.w) + bflo(vv.w) + b1p[6], 0.f) * w2p[6];
        acc += fmaxf(bfhi(uu.w) + bfhi(vv.w) + b1p[7], 0.f) * w2p[7];

        acc += __shfl_xor(acc, 1);
        acc += __shfl_xor(acc, 2);
        acc += __shfl_xor(acc, 4);
        acc += __shfl_xor(acc, 8);
        if (g == 0) out[e] = 1.f / (1.f + expf(-(acc + b2v)));
    }
}

// ---------------- fallback (R5-proven fp32-gather kernel) ----------------
__global__ __launch_bounds__(256, 3)
void lp_main(const float* __restrict__ z,
             const int* __restrict__ ei32,
             const float* __restrict__ W1,
             const float* __restrict__ b1,
             const float* __restrict__ W2,
             const float* __restrict__ b2,
             float* __restrict__ out,
             const int* __restrict__ flag,
             const uint4* __restrict__ wpack,
             int use_ws, int E, int ntiles)
{
    __shared__ uint4 ldsA_[64 * 512 / 16];
    __shared__ float part[4][64];
    char* ldsc = (char*)ldsA_;

    const int t = threadIdx.x, lane = t & 63, w = t >> 6;
    const int use64 = flag[0];

    uint4 Bf[8][2];
    if (use_ws) {
        #pragma unroll
        for (int kc = 0; kc < 8; ++kc)
            #pragma unroll
            for (int js = 0; js < 2; ++js)
                Bf[kc][js] = wpack[(kc * 8 + (w * 2 + js)) * 64 + lane];
    } else {
        #pragma unroll
        for (int kc = 0; kc < 8; ++kc)
            #pragma unroll
            for (int js = 0; js < 2; ++js) {
                const int k0 = kc * 32 + (lane >> 4) * 8;
                const int j  = (w * 2 + js) * 16 + (lane & 15);
                unsigned wv[4];
                #pragma unroll
                for (int p = 0; p < 4; ++p)
                    wv[p] = pk2bf(W1[(k0 + 2 * p) * HID + j],
                                  W1[(k0 + 2 * p + 1) * HID + j]);
                Bf[kc][js] = make_uint4(wv[0], wv[1], wv[2], wv[3]);
            }
    }

    const int e_r = lane & 15, q = lane >> 4, m16 = q * 16;
    const float b1v0 = b1[w * 32 + e_r], b1v1 = b1[w * 32 + 16 + e_r];
    const float w2v0 = W2[w * 32 + e_r], w2v1 = W2[w * 32 + 16 + e_r];
    const float b2v  = b2[0];

    for (int tile = blockIdx.x; tile < ntiles; tile += gridDim.x) {
        const int e0 = tile * 64;
        #pragma unroll 8
        for (int i = 0; i < 16; ++i) {
            const int el = i * 4 + w;
            int e = e0 + el; if (e > E - 1) e = E - 1;
            const int word = (lane < 32) ? e : (E + e);
            int node = ei32[(long long)word << use64];
            node = min(max(node, 0), NN - 1);
            const float4 v = *reinterpret_cast<const float4*>(
                &z[node * IN_DIM + (lane & 31) * 4]);
            const int byte = el * 512 + ((lane * 8) ^ ((el & 7) << 4));
            *reinterpret_cast<uint2*>(ldsc + byte) =
                make_uint2(pk2bf(v.x, v.y), pk2bf(v.z, v.w));
        }
        __syncthreads();

        f32x4 acc[4][2] = {};
        #pragma unroll
        for (int kc = 0; kc < 8; ++kc) {
            #pragma unroll
            for (int es = 0; es < 4; ++es) {
                const int row  = es * 16 + e_r;
                const int byte = row * 512 + ((kc * 64 + m16) ^ ((row & 7) << 4));
                const bf16x8 a = *reinterpret_cast<const bf16x8*>(ldsc + byte);
                acc[es][0] = __builtin_amdgcn_mfma_f32_16x16x32_bf16(
                    a, asbf(Bf[kc][0]), acc[es][0], 0, 0, 0);
                acc[es][1] = __builtin_amdgcn_mfma_f32_16x16x32_bf16(
                    a, asbf(Bf[kc][1]), acc[es][1], 0, 0, 0);
            }
        }

        float v16[16];
        #pragma unroll
        for (int es = 0; es < 4; ++es)
            #pragma unroll
            for (int reg = 0; reg < 4; ++reg)
                v16[es * 4 + reg] = fmaxf(acc[es][0][reg] + b1v0, 0.f) * w2v0
                                  + fmaxf(acc[es][1][reg] + b1v1, 0.f) * w2v1;
        #pragma unroll
        for (int rnd = 0; rnd < 4; ++rnd) {
            const int o = 1 << rnd, hl = 8 >> rnd;
            #pragma unroll
            for (int i = 0; i < hl; ++i) {
                const float a = v16[i], b = v16[i + hl];
                const float s = (lane & o) ? a : b;
                const float r = __shfl_xor(s, o);
                v16[i] = ((lane & o) ? b : a) + r;
            }
        }
        {
            const int lx  = lane & 15;
            const int idx = ((lx & 1) << 3) | ((lx & 2) << 1) | ((lx & 4) >> 1) | ((lx & 8) >> 3);
            const int edge = (idx >> 2) * 16 + q * 4 + (idx & 3);
            part[w][edge] = v16[0];
        }
        __syncthreads();

        if (t < 64) {
            const int e = e0 + t;
            if (e < E) {
                const float s = part[0][t] + part[1][t] + part[2][t] + part[3][t] + b2v;
                out[e] = 1.f / (1.f + expf(-s));
            }
        }
    }
}

extern "C" void kernel_launch(void* const* d_in, const int* in_sizes, int n_in,
                              void* d_out, int out_size, void* d_ws, size_t ws_size,
                              hipStream_t stream) {
    const float* z  = (const float*)d_in[0];
    const void*  ei = d_in[1];
    const float* W1 = (const float*)d_in[2];
    const float* b1 = (const float*)d_in[3];
    const float* W2 = (const float*)d_in[4];
    const float* b2 = (const float*)d_in[5];
    float* out = (float*)d_out;
    int*   flag  = (int*)d_ws;
    uint4* wpack = (uint4*)((char*)d_ws + WPACK_OFF);
    char*  ubf   = (char*)d_ws + UBF_OFF;
    char*  vbf   = (char*)d_ws + VBF_OFF;

    const int E = in_sizes[1] / 2;
    const int use_ws = (ws_size >= (size_t)(WPACK_OFF + WPACK_BYTES)) ? 1 : 0;
    const int use_uv = (ws_size >= (size_t)(VBF_OFF + VBF_BYTES)) ? 1 : 0;

    hipLaunchKernelGGL(prep, dim3(1), dim3(256), 0, stream,
                       W1, (const unsigned*)ei, wpack, flag, use_ws);

    if (use_uv) {
        const int ntiles = (NN + 63) / 64;                 // 1563
        const int g1 = (ntiles + 1) / 2;                   // 782: exactly <=2 tiles/block
        hipLaunchKernelGGL(uv_gemm, dim3(g1), dim3(256), 0, stream,
                           z, wpack, ubf, vbf, ntiles);
        hipLaunchKernelGGL(lp_edge, dim3(2048), dim3(256), 0, stream,
                           ubf, vbf, (const int*)ei, b1, W2, b2, out, flag, E);
    } else {
        const int ntiles = (E + 63) / 64;
        const int grid = (ntiles < 768) ? ntiles : 768;
        hipLaunchKernelGGL(lp_main, dim3(grid), dim3(256), 0, stream,
                           z, (const int*)ei, W1, b1, W2, b2, out, flag, wpack,
                           use_ws, E, ntiles);
    }
}